// Round 2
// baseline (343.538 us; speedup 1.0000x reference)
//
#include <hip/hip_runtime.h>
#include <stdint.h>

// TreeDecoder on MI355X.
// B=32, CN=1024, DEG=2, IN=OUT=128, NODES={1,16,128,1024}.
//
// Key algebraic fusions:
//  1) (X@Fw0+Fb0)@Fw1+Fb1 == X@(Fw0@Fw1) + (Fb0@Fw1+Fb1)  (no nonlinearity
//     between the Dense layers) -> precompute Ffused[128x128], Fbias[128].
//  2) anc (all 4 depth projections) + tree3@Uw3 == [t0|t1|t2|t3] (K=512)
//     @ [Uw0;Uw1;Uw2;Uw3] -> single MFMA GEMM per node block, lands in the
//     same C-layout as the output accumulators.
// Memory floor: W_up 134MB + tree3 17MB + out 33.5MB ~= 190MB -> ~30us.
//
// R1 post-mortem: memset+atomicAdd prelude double-accumulated Ffused under
// graph replay (absmax 2.89 ~= 5-sigma of the F-term => Ffused doubled).
// Prelude is now pure-overwrite (no atomics, no memset node in the graph):
// deterministic regardless of d_ws poison.

using short8   = __attribute__((ext_vector_type(8))) short;   // 8 x bf16
using floatx16 = __attribute__((ext_vector_type(16))) float;  // 32x32 acc

__device__ __forceinline__ unsigned short f2bf(float f) {
    unsigned int u = __builtin_bit_cast(unsigned int, f);
    return (unsigned short)((u + 0x8000u) >> 16);   // round-half-up, <=0.5ulp
}

// ---------------- prelude: Ffused = Fw0@Fw1, Fbias = Fb0@Fw1 + Fb1 ---------
// Grid 129 x 256 thr. Block i<128: row i of Ffused. Block 128: Fbias.
// Each output written exactly ONCE (deterministic two-term k-split reduce).
__global__ __launch_bounds__(256) void ffused_kernel(
    const float* __restrict__ Fw0, const float* __restrict__ Fb0,
    const float* __restrict__ Fw1, const float* __restrict__ Fb1,
    float* __restrict__ Ffused, float* __restrict__ Fbias)
{
    __shared__ float red[256];
    const int i = blockIdx.x;                 // 0..128
    const int j = threadIdx.x & 127;
    const int h = threadIdx.x >> 7;           // k-half
    const float* __restrict__ src = (i < 128) ? (Fw0 + (size_t)i * 1280) : Fb0;
    const int k0 = h * 640;
    float acc = 0.f;
    #pragma unroll 4
    for (int kk = 0; kk < 640; ++kk)
        acc += src[k0 + kk] * Fw1[(size_t)(k0 + kk) * 128 + j];
    red[threadIdx.x] = acc;
    __syncthreads();
    if (threadIdx.x < 128) {
        const float v = red[j] + red[128 + j];
        if (i < 128) Ffused[i * 128 + j] = v;
        else         Fbias[j] = v + Fb1[j];
    }
}

// ---------------- main: one block per node ---------------------------------
__global__ __launch_bounds__(256, 2) void tree_main(
    const float* __restrict__ t0, const float* __restrict__ t1,
    const float* __restrict__ t2, const float* __restrict__ t3,
    const float* __restrict__ Uw0, const float* __restrict__ Ub0,
    const float* __restrict__ Uw1, const float* __restrict__ Ub1,
    const float* __restrict__ Uw2, const float* __restrict__ Ub2,
    const float* __restrict__ Uw3, const float* __restrict__ Ub3,
    const float* __restrict__ Wup, const float* __restrict__ bbias,
    const float* __restrict__ Ffused, const float* __restrict__ Fbias,
    float* __restrict__ out)
{
    const int n    = blockIdx.x;        // node 0..1023
    const int tid  = threadIdx.x;
    const int w    = tid >> 6;          // wave 0..3
    const int lane = tid & 63;
    const int l31  = lane & 31;
    const int half = lane >> 5;

    // Unioned LDS (Acat phase 1 / Ulds phase 3): 33792 B -> up to 4 blk/CU.
    // Acat: [kgroup 64][m 32 pad 33][j 8] bf16  (rows = batch, K = 512 cat)
    // Ulds: [cgroup 16][r2 64 pad 65][j 8] bf16 (r2 = d*32 + b, K2 = 128)
    __shared__ __align__(16) unsigned short Smem[64 * 33 * 8];
    unsigned short* Acat = Smem;
    unsigned short* Ulds = Smem;

    // ---- stage [t0|t1|t2|t3] rows for all 32 batches -> Acat -------------
    #pragma unroll
    for (int i = 0; i < 16; ++i) {
        const int idx = i * 256 + tid;          // 0..4095 float4s
        const int b   = idx >> 7;               // batch
        const int q   = idx & 127;              // quad within 512-K row
        const int seg = q >> 5;                 // which tree
        const int kl  = (q & 31) * 4;           // k within 128
        const float* base; int row;
        if      (seg == 0) { base = t0; row = b; }
        else if (seg == 1) { base = t1; row = b * 16  + (n >> 6); }
        else if (seg == 2) { base = t2; row = b * 128 + (n >> 3); }
        else               { base = t3; row = b * 1024 + n; }
        const float4 v = *reinterpret_cast<const float4*>(base + (size_t)row * 128 + kl);
        ushort4 u;
        u.x = f2bf(v.x); u.y = f2bf(v.y); u.z = f2bf(v.z); u.w = f2bf(v.w);
        const int kg = q >> 1, j0 = (q & 1) * 4;
        *reinterpret_cast<ushort4*>(&Acat[(kg * 33 + b) * 8 + j0]) = u;
    }
    __syncthreads();

    // ---- GEMM 1: qacc = [t0|t1|t2|t3] @ [Uw0;Uw1;Uw2;Uw3]  (M32 N128 K512)
    // wave w owns output cols [32w, 32w+32). B-frags loaded straight from
    // global (8 coalesced dwords each: lanes 0..31 contiguous 128B).
    floatx16 qacc;
    #pragma unroll
    for (int r = 0; r < 16; ++r) qacc[r] = 0.f;
    const int colq = w * 32 + l31;
    short8 af[8];                        // retain tree3 A-frags for GEMM 2

    #pragma unroll
    for (int mi = 0; mi < 4; ++mi) {
        const float* Um = (mi == 0) ? Uw0 : (mi == 1) ? Uw1 : (mi == 2) ? Uw2 : Uw3;
        #pragma unroll
        for (int k8 = 0; k8 < 8; ++k8) {
            const int ks = mi * 8 + k8;
            const short8 a = *reinterpret_cast<const short8*>(
                &Acat[((2 * ks + half) * 33 + l31) * 8]);
            const int kloc = k8 * 16 + half * 8;
            const float* Up = Um + (size_t)kloc * 128 + colq;
            short8 bfr;
            #pragma unroll
            for (int jj = 0; jj < 8; ++jj) bfr[jj] = (short)f2bf(Up[jj * 128]);
            qacc = __builtin_amdgcn_mfma_f32_32x32x16_bf16(a, bfr, qacc, 0, 0, 0);
            if (mi == 3) af[k8] = a;
        }
    }
    __syncthreads();    // all Acat reads done before Ulds overlays Smem

    // ---- GEMM 2: U = tree3 @ W_up[n]   (M32 N256 K128), wave w owns cols
    // [64w, 64w+64) as two 32-wide tiles. W streamed straight from HBM.
    floatx16 acc0, acc1;
    #pragma unroll
    for (int r = 0; r < 16; ++r) { acc0[r] = 0.f; acc1[r] = 0.f; }
    const float* Wn = Wup + (size_t)n * 128 * 256;
    const int c0 = w * 64 + l31;
    #pragma unroll
    for (int ks = 0; ks < 8; ++ks) {
        const float* Wk = Wn + (size_t)(ks * 16 + half * 8) * 256;
        short8 b0, b1;
        #pragma unroll
        for (int jj = 0; jj < 8; ++jj) b0[jj] = (short)f2bf(Wk[jj * 256 + c0]);
        #pragma unroll
        for (int jj = 0; jj < 8; ++jj) b1[jj] = (short)f2bf(Wk[jj * 256 + c0 + 32]);
        acc0 = __builtin_amdgcn_mfma_f32_32x32x16_bf16(af[ks], b0, acc0, 0, 0, 0);
        acc1 = __builtin_amdgcn_mfma_f32_32x32x16_bf16(af[ks], b1, acc1, 0, 0, 0);
    }

    // ---- U -> LDS in A-fragment layout for GEMM 3 (r2 = d*32 + b) --------
    #pragma unroll
    for (int tt = 0; tt < 2; ++tt) {
        const floatx16 Av = tt ? acc1 : acc0;
        const int c  = (2 * w + tt) * 32 + l31;     // 0..255
        const int d  = c >> 7;
        const int cp = c & 127;
        const unsigned off0 = (unsigned)((((cp >> 3) * 65) + d * 32) * 8 + (cp & 7));
        #pragma unroll
        for (int r = 0; r < 16; ++r) {
            const int brow = (r & 3) + 8 * (r >> 2) + 4 * half;
            Ulds[off0 + (unsigned)brow * 8] = f2bf(Av[r]);
        }
    }
    __syncthreads();

    // ---- GEMM 3: out = U2 @ Ffused  (M64 N128 K128); wave w owns cols
    // [32w,32w+32) for both d-tiles (shares B-frags, aligns with qacc cols).
    floatx16 o0, o1;
    #pragma unroll
    for (int r = 0; r < 16; ++r) { o0[r] = 0.f; o1[r] = 0.f; }
    #pragma unroll
    for (int ks = 0; ks < 8; ++ks) {
        const int kb  = ks * 16 + half * 8;
        const int kg2 = kb >> 3;
        const short8 a0 = *reinterpret_cast<const short8*>(&Ulds[(kg2 * 65 + l31) * 8]);
        const short8 a1 = *reinterpret_cast<const short8*>(&Ulds[(kg2 * 65 + 32 + l31) * 8]);
        const float* Fp = Ffused + (size_t)kb * 128 + colq;
        short8 bfr;
        #pragma unroll
        for (int jj = 0; jj < 8; ++jj) bfr[jj] = (short)f2bf(Fp[jj * 128]);
        o0 = __builtin_amdgcn_mfma_f32_32x32x16_bf16(a0, bfr, o0, 0, 0, 0);
        o1 = __builtin_amdgcn_mfma_f32_32x32x16_bf16(a1, bfr, o1, 0, 0, 0);
    }

    // ---- epilogue: + anc(+Ub*) + Fbias + b_bias, LeakyReLU(0.2), store ---
    const float ubsum = Ub0[colq] + Ub1[colq] + Ub2[colq] + Ub3[colq] + Fbias[colq];
    const float bb0 = bbias[(size_t)(2 * n + 0) * 128 + colq];
    const float bb1 = bbias[(size_t)(2 * n + 1) * 128 + colq];
    #pragma unroll
    for (int r = 0; r < 16; ++r) {
        const int brow = (r & 3) + 8 * (r >> 2) + 4 * half;
        const float addc = qacc[r] + ubsum;
        float v0 = o0[r] + addc + bb0;
        float v1 = o1[r] + addc + bb1;
        v0 = (v0 >= 0.f) ? v0 : 0.2f * v0;
        v1 = (v1 >= 0.f) ? v1 : 0.2f * v1;
        const size_t idx0 = ((size_t)brow * 2048 + 2 * n) * 128 + colq;
        out[idx0]       = v0;
        out[idx0 + 128] = v1;
    }
}

extern "C" void kernel_launch(void* const* d_in, const int* in_sizes, int n_in,
                              void* d_out, int out_size, void* d_ws, size_t ws_size,
                              hipStream_t stream) {
    const float* t0  = (const float*)d_in[0];
    const float* t1  = (const float*)d_in[1];
    const float* t2  = (const float*)d_in[2];
    const float* t3  = (const float*)d_in[3];
    const float* Uw0 = (const float*)d_in[4];
    const float* Ub0 = (const float*)d_in[5];
    const float* Uw1 = (const float*)d_in[6];
    const float* Ub1 = (const float*)d_in[7];
    const float* Uw2 = (const float*)d_in[8];
    const float* Ub2 = (const float*)d_in[9];
    const float* Uw3 = (const float*)d_in[10];
    const float* Ub3 = (const float*)d_in[11];
    const float* Wup = (const float*)d_in[12];
    const float* Fw0 = (const float*)d_in[13];
    const float* Fb0 = (const float*)d_in[14];
    const float* Fw1 = (const float*)d_in[15];
    const float* Fb1 = (const float*)d_in[16];
    const float* bb  = (const float*)d_in[17];

    float* Ffused = (float*)d_ws;            // 128*128, fully overwritten
    float* Fbias  = Ffused + 128 * 128;      // 128, fully overwritten

    ffused_kernel<<<129, 256, 0, stream>>>(Fw0, Fb0, Fw1, Fb1, Ffused, Fbias);
    tree_main<<<1024, 256, 0, stream>>>(t0, t1, t2, t3,
                                        Uw0, Ub0, Uw1, Ub1, Uw2, Ub2, Uw3, Ub3,
                                        Wup, bb, Ffused, Fbias, (float*)d_out);
}

// Round 3
// 297.675 us; speedup vs baseline: 1.1541x; 1.1541x over previous
//
#include <hip/hip_runtime.h>
#include <stdint.h>

// TreeDecoder on MI355X. B=32, CN=1024, DEG=2, IN=OUT=128, NODES={1,16,128,1024}.
//
// Fusions:
//  1) (X@Fw0+Fb0)@Fw1+Fb1 == X@Ffused + Fbias  (no nonlinearity between).
//  2) anc + tree3@Uw3 == [t0|t1|t2|t3](K=512) @ [Uw0;Uw1;Uw2;Uw3] (one GEMM).
// R2 post-mortem: latency-bound (all pipes <16%). ~450 strided scalar dword
// loads + ~3.5K cvts per thread building B-frags. R3: precompute bf16
// B-frag-layout copies of Uw-cat and Ffused in ws (frag = ONE dwordx4),
// A-frags direct from global (k-contiguous), W_up staged via
// global_load_lds(16B) -> conflict-free ds_read_b32.

using short8   = __attribute__((ext_vector_type(8))) short;   // 8 x bf16
using floatx16 = __attribute__((ext_vector_type(16))) float;  // 32x32 acc

__device__ __forceinline__ unsigned short f2bf(float f) {
    unsigned int u = __builtin_bit_cast(unsigned int, f);
    return (unsigned short)((u + 0x8000u) >> 16);
}

__device__ __forceinline__ short8 cvt8(const float* p) {
    const float4 v0 = *reinterpret_cast<const float4*>(p);
    const float4 v1 = *reinterpret_cast<const float4*>(p + 4);
    short8 a;
    a[0] = (short)f2bf(v0.x); a[1] = (short)f2bf(v0.y);
    a[2] = (short)f2bf(v0.z); a[3] = (short)f2bf(v0.w);
    a[4] = (short)f2bf(v1.x); a[5] = (short)f2bf(v1.y);
    a[6] = (short)f2bf(v1.z); a[7] = (short)f2bf(v1.w);
    return a;
}

__device__ __forceinline__ void gl_lds16(const float* g, float* l) {
    __builtin_amdgcn_global_load_lds(
        (const __attribute__((address_space(1))) unsigned int*)g,
        (__attribute__((address_space(3))) unsigned int*)l, 16, 0, 0);
}

// ws layout (floats):
//  P        [16][129][128] partials            @ 0        (264192)
//  Fbias    [128]                              @ 264192
//  FfusedBF [16][128][8] ushort (8192 floats)  @ 264320
//  UwBF     [4][16][128][8] ushort (32768 fl)  @ 272512
#define P_FLOATS  264192
#define FB_OFF    264192
#define FF_OFF    264320
#define UW_OFF    272512

// ---- ffused stage 1: 80-MAC partials, overwrite-only. grid(8,129) --------
__global__ __launch_bounds__(256) void ffused_p1(
    const float* __restrict__ Fw0, const float* __restrict__ Fb0,
    const float* __restrict__ Fw1, float* __restrict__ P)
{
    const int kc = blockIdx.x;            // 0..7
    const int i  = blockIdx.y;            // 0..128 (128 = bias row)
    const int j  = threadIdx.x & 127;
    const int il = threadIdx.x >> 7;      // half of the 160-k chunk
    const int k0 = kc * 160 + il * 80;
    const float* __restrict__ src = (i < 128) ? (Fw0 + (size_t)i * 1280) : Fb0;
    float acc = 0.f;
    #pragma unroll 8
    for (int kk = 0; kk < 80; ++kk)
        acc += src[k0 + kk] * Fw1[(size_t)(k0 + kk) * 128 + j];
    P[(size_t)(kc * 2 + il) * 16512 + i * 128 + j] = acc;
}

// ---- ffused stage 2: reduce 16 partials -> FfusedBF (frag layout) + Fbias -
__global__ __launch_bounds__(256) void ffused_p2(
    const float* __restrict__ P, const float* __restrict__ Fb1,
    unsigned short* __restrict__ FfusedBF, float* __restrict__ Fbias)
{
    const int idx = blockIdx.x * 256 + threadIdx.x;
    if (idx >= 16512) return;
    const int i = idx >> 7, j = idx & 127;
    float s = 0.f;
    #pragma unroll
    for (int p = 0; p < 16; ++p) s += P[(size_t)p * 16512 + idx];
    if (i < 128) FfusedBF[(((i >> 3) * 128) + j) * 8 + (i & 7)] = f2bf(s);
    else         Fbias[j] = s + Fb1[j];
}

// ---- Uw cat -> bf16 B-frag layout. grid 64 = (mat 4) x (kg 16) -----------
__global__ __launch_bounds__(256) void uwbf_kernel(
    const float* __restrict__ Uw0, const float* __restrict__ Uw1,
    const float* __restrict__ Uw2, const float* __restrict__ Uw3,
    unsigned short* __restrict__ UwBF)
{
    const int mat = blockIdx.x >> 4;
    const int kg  = blockIdx.x & 15;
    const float* __restrict__ Uw = (mat == 0) ? Uw0 : (mat == 1) ? Uw1
                                 : (mat == 2) ? Uw2 : Uw3;
    const int col = threadIdx.x & 127;
    const int kh  = threadIdx.x >> 7;
    #pragma unroll
    for (int q = 0; q < 4; ++q) {
        const int kk = kh * 4 + q;
        const float v = Uw[(size_t)(kg * 8 + kk) * 128 + col];
        UwBF[(((size_t)(mat * 16 + kg) * 128) + col) * 8 + kk] = f2bf(v);
    }
}

// ---------------- main: one block per node ---------------------------------
__global__ __launch_bounds__(256, 2) void tree_main(
    const float* __restrict__ t0, const float* __restrict__ t1,
    const float* __restrict__ t2, const float* __restrict__ t3,
    const float* __restrict__ Ub0, const float* __restrict__ Ub1,
    const float* __restrict__ Ub2, const float* __restrict__ Ub3,
    const float* __restrict__ Wup, const float* __restrict__ bbias,
    const unsigned short* __restrict__ FfusedBF,
    const unsigned short* __restrict__ UwBF,
    const float* __restrict__ Fbias,
    float* __restrict__ out)
{
    const int n    = blockIdx.x;
    const int tid  = threadIdx.x;
    const int w    = tid >> 6;
    const int lane = tid & 63;
    const int l31  = lane & 31;
    const int half = lane >> 5;
    const int colq = w * 32 + l31;

    // Union: Wlds (16k x 256c fp32, 16384B) / Ulds (16x65x8 ushort, 16640B)
    __shared__ __align__(16) unsigned char smem_raw[16640];
    float*          Wlds = (float*)smem_raw;
    unsigned short* Ulds = (unsigned short*)smem_raw;

    // ---- GEMM 1: qacc = [t0|t1|t2|t3] @ Uwcat  (M32 N128 K512) ----------
    // A-frags direct from global (rows k-contiguous); B-frags = one dwordx4
    // from precomputed UwBF. Keep t3 frags (mi==3) as af for GEMM 2/3.
    floatx16 qacc;
    #pragma unroll
    for (int r = 0; r < 16; ++r) qacc[r] = 0.f;
    short8 af[8];
    const int b = l31;                     // A row = batch

    #pragma unroll
    for (int mi = 0; mi < 4; ++mi) {
        const float* base; int row;
        if      (mi == 0) { base = t0; row = b; }
        else if (mi == 1) { base = t1; row = b * 16 + (n >> 6); }
        else if (mi == 2) { base = t2; row = b * 128 + (n >> 3); }
        else              { base = t3; row = b * 1024 + n; }
        const float* rp = base + (size_t)row * 128;
        #pragma unroll
        for (int k8 = 0; k8 < 8; ++k8) {
            const short8 a = cvt8(rp + k8 * 16 + half * 8);
            const short8 bf = *reinterpret_cast<const short8*>(
                &UwBF[(((size_t)(mi * 16 + 2 * k8 + half) * 128) + colq) * 8]);
            qacc = __builtin_amdgcn_mfma_f32_32x32x16_bf16(a, bf, qacc, 0, 0, 0);
            if (mi == 3) af[k8] = a;
        }
    }

    // ---- GEMM 2: U = tree3 @ W_up[n]  (M32 N256 K128) --------------------
    // W staged in 16-k chunks via async global_load_lds (16B/lane), frags
    // via conflict-free ds_read_b32. Wave w owns cols [64w,64w+64).
    floatx16 acc0, acc1;
    #pragma unroll
    for (int r = 0; r < 16; ++r) { acc0[r] = 0.f; acc1[r] = 0.f; }
    const float* Wn = Wup + (size_t)n * 32768;
    const int c0 = w * 64 + l31;
    #pragma unroll
    for (int ks = 0; ks < 8; ++ks) {
        __syncthreads();                       // prev chunk reads done
        #pragma unroll
        for (int inst = 0; inst < 4; ++inst)
            gl_lds16(Wn + (size_t)ks * 4096 + inst * 1024 + tid * 4,
                     &Wlds[inst * 1024 + tid * 4]);
        __syncthreads();                       // glds drained (vmcnt0 @ barrier)
        short8 b0, b1;
        #pragma unroll
        for (int jj = 0; jj < 8; ++jj) {
            const int krow = (half * 8 + jj) * 256;
            b0[jj] = (short)f2bf(Wlds[krow + c0]);
            b1[jj] = (short)f2bf(Wlds[krow + c0 + 32]);
        }
        acc0 = __builtin_amdgcn_mfma_f32_32x32x16_bf16(af[ks], b0, acc0, 0, 0, 0);
        acc1 = __builtin_amdgcn_mfma_f32_32x32x16_bf16(af[ks], b1, acc1, 0, 0, 0);
    }
    __syncthreads();                           // Wlds reads done before Ulds

    // ---- U -> LDS in A-frag layout (r2 = d*32 + batch) -------------------
    #pragma unroll
    for (int tt = 0; tt < 2; ++tt) {
        const floatx16 Av = tt ? acc1 : acc0;
        const int c  = (2 * w + tt) * 32 + l31;     // 0..255
        const int d  = c >> 7;
        const int cp = c & 127;
        const unsigned off0 = (unsigned)((((cp >> 3) * 65) + d * 32) * 8 + (cp & 7));
        #pragma unroll
        for (int r = 0; r < 16; ++r) {
            const int brow = (r & 3) + 8 * (r >> 2) + 4 * half;
            Ulds[off0 + (unsigned)brow * 8] = f2bf(Av[r]);
        }
    }
    __syncthreads();

    // ---- GEMM 3: out = U2 @ Ffused  (M64 N128 K128) ----------------------
    floatx16 o0, o1;
    #pragma unroll
    for (int r = 0; r < 16; ++r) { o0[r] = 0.f; o1[r] = 0.f; }
    #pragma unroll
    for (int ks = 0; ks < 8; ++ks) {
        const int kg2 = 2 * ks + half;
        const short8 a0 = *reinterpret_cast<const short8*>(&Ulds[(kg2 * 65 + l31) * 8]);
        const short8 a1 = *reinterpret_cast<const short8*>(&Ulds[(kg2 * 65 + 32 + l31) * 8]);
        const short8 bf = *reinterpret_cast<const short8*>(
            &FfusedBF[(((size_t)kg2 * 128) + colq) * 8]);
        o0 = __builtin_amdgcn_mfma_f32_32x32x16_bf16(a0, bf, o0, 0, 0, 0);
        o1 = __builtin_amdgcn_mfma_f32_32x32x16_bf16(a1, bf, o1, 0, 0, 0);
    }

    // ---- epilogue --------------------------------------------------------
    const float ubsum = Ub0[colq] + Ub1[colq] + Ub2[colq] + Ub3[colq] + Fbias[colq];
    const float bb0 = bbias[(size_t)(2 * n + 0) * 128 + colq];
    const float bb1 = bbias[(size_t)(2 * n + 1) * 128 + colq];
    #pragma unroll
    for (int r = 0; r < 16; ++r) {
        const int brow = (r & 3) + 8 * (r >> 2) + 4 * half;
        const float addc = qacc[r] + ubsum;
        float v0 = o0[r] + addc + bb0;
        float v1 = o1[r] + addc + bb1;
        v0 = (v0 >= 0.f) ? v0 : 0.2f * v0;
        v1 = (v1 >= 0.f) ? v1 : 0.2f * v1;
        const size_t idx0 = ((size_t)brow * 2048 + 2 * n) * 128 + colq;
        out[idx0]       = v0;
        out[idx0 + 128] = v1;
    }
}

extern "C" void kernel_launch(void* const* d_in, const int* in_sizes, int n_in,
                              void* d_out, int out_size, void* d_ws, size_t ws_size,
                              hipStream_t stream) {
    const float* t0  = (const float*)d_in[0];
    const float* t1  = (const float*)d_in[1];
    const float* t2  = (const float*)d_in[2];
    const float* t3  = (const float*)d_in[3];
    const float* Uw0 = (const float*)d_in[4];
    const float* Ub0 = (const float*)d_in[5];
    const float* Uw1 = (const float*)d_in[6];
    const float* Ub1 = (const float*)d_in[7];
    const float* Uw2 = (const float*)d_in[8];
    const float* Ub2 = (const float*)d_in[9];
    const float* Uw3 = (const float*)d_in[10];
    const float* Ub3 = (const float*)d_in[11];
    const float* Wup = (const float*)d_in[12];
    const float* Fw0 = (const float*)d_in[13];
    const float* Fb0 = (const float*)d_in[14];
    const float* Fw1 = (const float*)d_in[15];
    const float* Fb1 = (const float*)d_in[16];
    const float* bb  = (const float*)d_in[17];

    float* ws = (float*)d_ws;
    float* P              = ws;
    float* Fbias          = ws + FB_OFF;
    unsigned short* FfBF  = (unsigned short*)(ws + FF_OFF);
    unsigned short* UwBF  = (unsigned short*)(ws + UW_OFF);

    ffused_p1<<<dim3(8, 129), 256, 0, stream>>>(Fw0, Fb0, Fw1, P);
    ffused_p2<<<65, 256, 0, stream>>>(P, Fb1, FfBF, Fbias);
    uwbf_kernel<<<64, 256, 0, stream>>>(Uw0, Uw1, Uw2, Uw3, UwBF);
    tree_main<<<1024, 256, 0, stream>>>(t0, t1, t2, t3,
                                        Ub0, Ub1, Ub2, Ub3,
                                        Wup, bb, FfBF, UwBF, Fbias,
                                        (float*)d_out);
}

// Round 4
// 283.816 us; speedup vs baseline: 1.2104x; 1.0488x over previous
//
#include <hip/hip_runtime.h>
#include <stdint.h>

// TreeDecoder on MI355X. B=32, CN=1024, DEG=2, IN=OUT=128, NODES={1,16,128,1024}.
//
// Fusions:
//  1) (X@Fw0+Fb0)@Fw1+Fb1 == X@Ffused + Fbias (no nonlinearity between).
//  2) anc(t0,t1,t2) precomputed once as Qsum[b,i2,:] (prelude, 2MB ws) --
//     was duplicated x1024 blocks with uncoalesced loads (R3 bottleneck).
//  3) GEMM2 computed as U^T = W^T @ t3^T: W is the MFMA *A*-operand, so its
//     fragments load DIRECTLY from global fully coalesced (lanes->columns).
//     No LDS staging, no barriers in the W stream (R3's vmcnt(0) drains gone).
// Per-block: stage t3 (coalesced) -> fused K-loop (3 MFMAs/ks: qacc + 2 U^T
// tiles, W prefetched depth-1) -> LDS transpose -> GEMM3 -> epilogue.

using short8   = __attribute__((ext_vector_type(8))) short;   // 8 x bf16
using floatx16 = __attribute__((ext_vector_type(16))) float;  // 32x32 acc

__device__ __forceinline__ unsigned short f2bf(float f) {
    unsigned int u = __builtin_bit_cast(unsigned int, f);
    return (unsigned short)((u + 0x8000u) >> 16);
}

__device__ __forceinline__ short8 cvt8(const float* p) {
    const float4 v0 = *reinterpret_cast<const float4*>(p);
    const float4 v1 = *reinterpret_cast<const float4*>(p + 4);
    short8 a;
    a[0] = (short)f2bf(v0.x); a[1] = (short)f2bf(v0.y);
    a[2] = (short)f2bf(v0.z); a[3] = (short)f2bf(v0.w);
    a[4] = (short)f2bf(v1.x); a[5] = (short)f2bf(v1.y);
    a[6] = (short)f2bf(v1.z); a[7] = (short)f2bf(v1.w);
    return a;
}

// ws layout (float offsets). Qsum overlays P (P dead after ffused_p2).
//  Qsum/P [32][128][128]     @ 0       (524288 fl; P uses first 264192)
//  Fbias  [128]              @ 524288
//  FfusedBF [16][128][8] u16 @ 524416  (8192 fl)
//  UwBF [4][16][128][8] u16  @ 532608  (32768 fl)
#define QS_OFF  0
#define FB_OFF  524288
#define FF_OFF  524416
#define UW_OFF  532608

// ---- ffused stage 1: 80-MAC partials, overwrite-only. grid(8,129) --------
__global__ __launch_bounds__(256) void ffused_p1(
    const float* __restrict__ Fw0, const float* __restrict__ Fb0,
    const float* __restrict__ Fw1, float* __restrict__ P)
{
    const int kc = blockIdx.x;            // 0..7
    const int i  = blockIdx.y;            // 0..128 (128 = bias row)
    const int j  = threadIdx.x & 127;
    const int il = threadIdx.x >> 7;
    const int k0 = kc * 160 + il * 80;
    const float* __restrict__ src = (i < 128) ? (Fw0 + (size_t)i * 1280) : Fb0;
    float acc = 0.f;
    #pragma unroll 8
    for (int kk = 0; kk < 80; ++kk)
        acc += src[k0 + kk] * Fw1[(size_t)(k0 + kk) * 128 + j];
    P[(size_t)(kc * 2 + il) * 16512 + i * 128 + j] = acc;
}

// ---- ffused stage 2: reduce 16 partials -> FfusedBF (frag layout) + Fbias -
__global__ __launch_bounds__(256) void ffused_p2(
    const float* __restrict__ P, const float* __restrict__ Fb1,
    unsigned short* __restrict__ FfusedBF, float* __restrict__ Fbias)
{
    const int idx = blockIdx.x * 256 + threadIdx.x;
    if (idx >= 16512) return;
    const int i = idx >> 7, j = idx & 127;
    float s = 0.f;
    #pragma unroll
    for (int p = 0; p < 16; ++p) s += P[(size_t)p * 16512 + idx];
    if (i < 128) FfusedBF[(((i >> 3) * 128) + j) * 8 + (i & 7)] = f2bf(s);
    else         Fbias[j] = s + Fb1[j];
}

// ---- Uw cat -> bf16 B-frag layout. grid 64 = (mat 4) x (kg 16) -----------
__global__ __launch_bounds__(256) void uwbf_kernel(
    const float* __restrict__ Uw0, const float* __restrict__ Uw1,
    const float* __restrict__ Uw2, const float* __restrict__ Uw3,
    unsigned short* __restrict__ UwBF)
{
    const int mat = blockIdx.x >> 4;
    const int kg  = blockIdx.x & 15;
    const float* __restrict__ Uw = (mat == 0) ? Uw0 : (mat == 1) ? Uw1
                                 : (mat == 2) ? Uw2 : Uw3;
    const int col = threadIdx.x & 127;
    const int kh  = threadIdx.x >> 7;
    #pragma unroll
    for (int q = 0; q < 4; ++q) {
        const int kk = kh * 4 + q;
        const float v = Uw[(size_t)(kg * 8 + kk) * 128 + col];
        UwBF[(((size_t)(mat * 16 + kg) * 128) + col) * 8 + kk] = f2bf(v);
    }
}

// ---- Qsum prelude: Qsum[b,i2,:] = t0[b]@Uw0 + t1[b,i2>>3]@Uw1 + t2[b,i2]@Uw2
// grid 128 (one block per i2), M=32 b, N=128, K=384. 0.2 GMAC total.
__global__ __launch_bounds__(256) void qsum_kernel(
    const float* __restrict__ t0, const float* __restrict__ t1,
    const float* __restrict__ t2, const unsigned short* __restrict__ UwBF,
    float* __restrict__ Qsum)
{
    const int i2   = blockIdx.x;
    const int tid  = threadIdx.x;
    const int w    = tid >> 6;
    const int lane = tid & 63;
    const int l31  = lane & 31;
    const int half = lane >> 5;
    const int colq = w * 32 + l31;
    const int b    = l31;

    floatx16 acc;
    #pragma unroll
    for (int r = 0; r < 16; ++r) acc[r] = 0.f;

    #pragma unroll
    for (int mi = 0; mi < 3; ++mi) {
        const float* base; int row;
        if      (mi == 0) { base = t0; row = b; }
        else if (mi == 1) { base = t1; row = b * 16 + (i2 >> 3); }
        else              { base = t2; row = b * 128 + i2; }
        const float* rp = base + (size_t)row * 128;
        #pragma unroll
        for (int k8 = 0; k8 < 8; ++k8) {
            const short8 a  = cvt8(rp + k8 * 16 + half * 8);
            const short8 bf = *reinterpret_cast<const short8*>(
                &UwBF[(((size_t)(mi * 16 + 2 * k8 + half) * 128) + colq) * 8]);
            acc = __builtin_amdgcn_mfma_f32_32x32x16_bf16(a, bf, acc, 0, 0, 0);
        }
    }
    #pragma unroll
    for (int r = 0; r < 16; ++r) {
        const int brow = (r & 3) + 8 * (r >> 2) + 4 * half;
        Qsum[((size_t)brow * 128 + i2) * 128 + colq] = acc[r];
    }
}

// ---------------- main: one block per node ---------------------------------
__global__ __launch_bounds__(256, 2) void tree_main(
    const float* __restrict__ t3,
    const float* __restrict__ Ub0, const float* __restrict__ Ub1,
    const float* __restrict__ Ub2, const float* __restrict__ Ub3,
    const float* __restrict__ Wup, const float* __restrict__ bbias,
    const unsigned short* __restrict__ FfusedBF,
    const unsigned short* __restrict__ UwBF,
    const float* __restrict__ Fbias, const float* __restrict__ Qsum,
    float* __restrict__ out)
{
    const int n    = blockIdx.x;
    const int tid  = threadIdx.x;
    const int w    = tid >> 6;
    const int lane = tid & 63;
    const int l31  = lane & 31;
    const int half = lane >> 5;
    const int colq = w * 32 + l31;

    // Union: T3lds [16 kg][33][8] u16 (8448B) / Ulds [16][65][8] u16 (16640B)
    __shared__ __align__(16) unsigned char smem_raw[16640];
    unsigned short* T3lds = (unsigned short*)smem_raw;
    unsigned short* Ulds  = (unsigned short*)smem_raw;

    // ---- stage t3 rows (32 b x 128 k) coalesced -> A-frag layout ---------
    #pragma unroll
    for (int i = 0; i < 4; ++i) {
        const int idx = i * 256 + tid;        // 0..1023 float4s
        const int b   = idx >> 5;
        const int q   = idx & 31;
        const float4 v = *reinterpret_cast<const float4*>(
            t3 + ((size_t)b * 1024 + n) * 128 + q * 4);
        ushort4 u;
        u.x = f2bf(v.x); u.y = f2bf(v.y); u.z = f2bf(v.z); u.w = f2bf(v.w);
        *reinterpret_cast<ushort4*>(&T3lds[((q >> 1) * 33 + b) * 8 + (q & 1) * 4]) = u;
    }
    __syncthreads();

    // ---- fused K-loop over t3's K=128 (8 steps of 16) --------------------
    // per ks: afk (1 ds_read_b128) feeds 3 MFMAs:
    //   qacc  += afk @ Uw3frag           (C: col=j, row=batch)
    //   accT0 += Wfrag(c0)  @ afk        (U^T tile: col=batch, row=c-off)
    //   accT1 += Wfrag(c0+32) @ afk
    // W-fragments: 8 coalesced global dwords each (lanes->consecutive cols),
    // prefetched depth-1 -> no stalls chained to MFMAs.
    floatx16 qacc, accT0, accT1;
    #pragma unroll
    for (int r = 0; r < 16; ++r) { qacc[r] = 0.f; accT0[r] = 0.f; accT1[r] = 0.f; }

    const float* __restrict__ Wp0 = Wup + (size_t)n * 32768 + (half * 8) * 256 + w * 64 + l31;
    const float* __restrict__ Wp1 = Wp0 + 32;

    float p0[8], p1[8];
    #pragma unroll
    for (int jj = 0; jj < 8; ++jj) { p0[jj] = Wp0[jj * 256]; p1[jj] = Wp1[jj * 256]; }

    #pragma unroll
    for (int ks = 0; ks < 8; ++ks) {
        float n0[8], n1[8];
        if (ks < 7) {
            const int koff = (ks + 1) * 16 * 256;
            #pragma unroll
            for (int jj = 0; jj < 8; ++jj) {
                n0[jj] = Wp0[koff + jj * 256];
                n1[jj] = Wp1[koff + jj * 256];
            }
        }
        const short8 afk = *reinterpret_cast<const short8*>(
            &T3lds[((2 * ks + half) * 33 + l31) * 8]);
        const short8 bfu = *reinterpret_cast<const short8*>(
            &UwBF[(((size_t)(48 + 2 * ks + half) * 128) + colq) * 8]);
        short8 a0, a1;
        #pragma unroll
        for (int jj = 0; jj < 8; ++jj) {
            a0[jj] = (short)f2bf(p0[jj]);
            a1[jj] = (short)f2bf(p1[jj]);
        }
        qacc  = __builtin_amdgcn_mfma_f32_32x32x16_bf16(afk, bfu, qacc, 0, 0, 0);
        accT0 = __builtin_amdgcn_mfma_f32_32x32x16_bf16(a0, afk, accT0, 0, 0, 0);
        accT1 = __builtin_amdgcn_mfma_f32_32x32x16_bf16(a1, afk, accT1, 0, 0, 0);
        #pragma unroll
        for (int jj = 0; jj < 8; ++jj) { p0[jj] = n0[jj]; p1[jj] = n1[jj]; }
    }
    __syncthreads();     // all T3lds reads done before Ulds overlays

    // ---- U^T accs -> Ulds in GEMM3 A-frag layout (r2 = d*32 + batch) -----
    #pragma unroll
    for (int tt = 0; tt < 2; ++tt) {
        const floatx16 Av = tt ? accT1 : accT0;
        #pragma unroll
        for (int r = 0; r < 16; ++r) {
            const int cm = w * 64 + tt * 32 + ((r & 3) + 8 * (r >> 2) + 4 * half);
            const int d  = cm >> 7;
            const int cp = cm & 127;
            Ulds[(((cp >> 3) * 65) + d * 32 + l31) * 8 + (cp & 7)] = f2bf(Av[r]);
        }
    }
    __syncthreads();

    // ---- GEMM 3: out = U2 @ Ffused  (M64 N128 K128) ----------------------
    floatx16 o0, o1;
    #pragma unroll
    for (int r = 0; r < 16; ++r) { o0[r] = 0.f; o1[r] = 0.f; }
    #pragma unroll
    for (int ks = 0; ks < 8; ++ks) {
        const int kg2 = 2 * ks + half;
        const short8 a0 = *reinterpret_cast<const short8*>(&Ulds[(kg2 * 65 + l31) * 8]);
        const short8 a1 = *reinterpret_cast<const short8*>(&Ulds[(kg2 * 65 + 32 + l31) * 8]);
        const short8 bf = *reinterpret_cast<const short8*>(
            &FfusedBF[(((size_t)kg2 * 128) + colq) * 8]);
        o0 = __builtin_amdgcn_mfma_f32_32x32x16_bf16(a0, bf, o0, 0, 0, 0);
        o1 = __builtin_amdgcn_mfma_f32_32x32x16_bf16(a1, bf, o1, 0, 0, 0);
    }

    // ---- epilogue: + qacc + Qsum + biases, LeakyReLU(0.2), store ---------
    const float ubsum = Ub0[colq] + Ub1[colq] + Ub2[colq] + Ub3[colq] + Fbias[colq];
    const float bb0 = bbias[(size_t)(2 * n + 0) * 128 + colq];
    const float bb1 = bbias[(size_t)(2 * n + 1) * 128 + colq];
    const int i2 = n >> 3;
    #pragma unroll
    for (int r = 0; r < 16; ++r) {
        const int brow = (r & 3) + 8 * (r >> 2) + 4 * half;
        const float addc = qacc[r] + ubsum + Qsum[((size_t)brow * 128 + i2) * 128 + colq];
        float v0 = o0[r] + addc + bb0;
        float v1 = o1[r] + addc + bb1;
        v0 = (v0 >= 0.f) ? v0 : 0.2f * v0;
        v1 = (v1 >= 0.f) ? v1 : 0.2f * v1;
        const size_t idx0 = ((size_t)brow * 2048 + 2 * n) * 128 + colq;
        out[idx0]       = v0;
        out[idx0 + 128] = v1;
    }
}

extern "C" void kernel_launch(void* const* d_in, const int* in_sizes, int n_in,
                              void* d_out, int out_size, void* d_ws, size_t ws_size,
                              hipStream_t stream) {
    const float* t0  = (const float*)d_in[0];
    const float* t1  = (const float*)d_in[1];
    const float* t2  = (const float*)d_in[2];
    const float* t3  = (const float*)d_in[3];
    const float* Uw0 = (const float*)d_in[4];
    const float* Ub0 = (const float*)d_in[5];
    const float* Uw1 = (const float*)d_in[6];
    const float* Ub1 = (const float*)d_in[7];
    const float* Uw2 = (const float*)d_in[8];
    const float* Ub2 = (const float*)d_in[9];
    const float* Uw3 = (const float*)d_in[10];
    const float* Ub3 = (const float*)d_in[11];
    const float* Wup = (const float*)d_in[12];
    const float* Fw0 = (const float*)d_in[13];
    const float* Fb0 = (const float*)d_in[14];
    const float* Fw1 = (const float*)d_in[15];
    const float* Fb1 = (const float*)d_in[16];
    const float* bb  = (const float*)d_in[17];

    float* ws = (float*)d_ws;
    float* Qsum           = ws + QS_OFF;     // overlays P (dead after p2)
    float* Fbias          = ws + FB_OFF;
    unsigned short* FfBF  = (unsigned short*)(ws + FF_OFF);
    unsigned short* UwBF  = (unsigned short*)(ws + UW_OFF);

    ffused_p1<<<dim3(8, 129), 256, 0, stream>>>(Fw0, Fb0, Fw1, Qsum);
    ffused_p2<<<65, 256, 0, stream>>>(Qsum, Fb1, FfBF, Fbias);
    uwbf_kernel<<<64, 256, 0, stream>>>(Uw0, Uw1, Uw2, Uw3, UwBF);
    qsum_kernel<<<128, 256, 0, stream>>>(t0, t1, t2, UwBF, Qsum);
    tree_main<<<1024, 256, 0, stream>>>(t3,
                                        Ub0, Ub1, Ub2, Ub3,
                                        Wup, bb, FfBF, UwBF, Fbias, Qsum,
                                        (float*)d_out);
}

// Round 5
// 268.090 us; speedup vs baseline: 1.2814x; 1.0587x over previous
//
#include <hip/hip_runtime.h>
#include <stdint.h>

// TreeDecoder on MI355X. B=32, CN=1024, DEG=2, IN=OUT=128, NODES={1,16,128,1024}.
//
// Fusions:
//  1) (X@Fw0+Fb0)@Fw1+Fb1 == X@Ffused + Fbias (no nonlinearity between).
//  2) anc(t0,t1,t2) precomputed once as Qsum[i2,b,:] (prelude, 2MB ws).
//  3) GEMM2 computed as U^T = W^T @ t3^T: W is the MFMA *A*-operand ->
//     fragments load DIRECTLY from global coalesced, no barriers in W stream.
// R4 post-mortem: tree_main fell below the 78us d_ws-poison fills (harness
// fixed overhead dominates dur_us). R5: qsum staged via LDS (its divergent
// dwordx4 loads serialized in the TA), Qsum layout flipped to [i2][brow][col]
// (contiguous 16KB/block, L2-shared by 8 blocks), epilogue operands
// prefetched before GEMM3.

using short8   = __attribute__((ext_vector_type(8))) short;   // 8 x bf16
using floatx16 = __attribute__((ext_vector_type(16))) float;  // 32x32 acc

__device__ __forceinline__ unsigned short f2bf(float f) {
    unsigned int u = __builtin_bit_cast(unsigned int, f);
    return (unsigned short)((u + 0x8000u) >> 16);
}

// ws layout (float offsets). Qsum overlays P (P dead after ffused_p2).
//  Qsum/P [128][32][128]     @ 0       (524288 fl; P uses first 264192)
//  Fbias  [128]              @ 524288
//  FfusedBF [16][128][8] u16 @ 524416  (8192 fl)
//  UwBF [4][16][128][8] u16  @ 532608  (32768 fl)
#define QS_OFF  0
#define FB_OFF  524288
#define FF_OFF  524416
#define UW_OFF  532608

// ---- ffused stage 1: 80-MAC partials, overwrite-only. grid(8,129) --------
__global__ __launch_bounds__(256) void ffused_p1(
    const float* __restrict__ Fw0, const float* __restrict__ Fb0,
    const float* __restrict__ Fw1, float* __restrict__ P)
{
    const int kc = blockIdx.x;            // 0..7
    const int i  = blockIdx.y;            // 0..128 (128 = bias row)
    const int j  = threadIdx.x & 127;
    const int il = threadIdx.x >> 7;
    const int k0 = kc * 160 + il * 80;
    const float* __restrict__ src = (i < 128) ? (Fw0 + (size_t)i * 1280) : Fb0;
    float acc = 0.f;
    #pragma unroll 8
    for (int kk = 0; kk < 80; ++kk)
        acc += src[k0 + kk] * Fw1[(size_t)(k0 + kk) * 128 + j];
    P[(size_t)(kc * 2 + il) * 16512 + i * 128 + j] = acc;
}

// ---- ffused stage 2: reduce 16 partials -> FfusedBF (frag layout) + Fbias -
__global__ __launch_bounds__(256) void ffused_p2(
    const float* __restrict__ P, const float* __restrict__ Fb1,
    unsigned short* __restrict__ FfusedBF, float* __restrict__ Fbias)
{
    const int idx = blockIdx.x * 256 + threadIdx.x;
    if (idx >= 16512) return;
    const int i = idx >> 7, j = idx & 127;
    float s = 0.f;
    #pragma unroll
    for (int p = 0; p < 16; ++p) s += P[(size_t)p * 16512 + idx];
    if (i < 128) FfusedBF[(((i >> 3) * 128) + j) * 8 + (i & 7)] = f2bf(s);
    else         Fbias[j] = s + Fb1[j];
}

// ---- Uw cat -> bf16 B-frag layout. grid 64 = (mat 4) x (kg 16) -----------
__global__ __launch_bounds__(256) void uwbf_kernel(
    const float* __restrict__ Uw0, const float* __restrict__ Uw1,
    const float* __restrict__ Uw2, const float* __restrict__ Uw3,
    unsigned short* __restrict__ UwBF)
{
    const int mat = blockIdx.x >> 4;
    const int kg  = blockIdx.x & 15;
    const float* __restrict__ Uw = (mat == 0) ? Uw0 : (mat == 1) ? Uw1
                                 : (mat == 2) ? Uw2 : Uw3;
    const int col = threadIdx.x & 127;
    const int kh  = threadIdx.x >> 7;
    #pragma unroll
    for (int q = 0; q < 4; ++q) {
        const int kk = kh * 4 + q;
        const float v = Uw[(size_t)(kg * 8 + kk) * 128 + col];
        UwBF[(((size_t)(mat * 16 + kg) * 128) + col) * 8 + kk] = f2bf(v);
    }
}

// ---- Qsum prelude: Qsum[i2,b,:] = t0[b]@Uw0 + t1[b,i2>>3]@Uw1 + t2[b,i2]@Uw2
// grid 128 (one block per i2). t-rows staged coalesced -> LDS A-frag layout
// (R4's divergent per-lane dwordx4 loads serialized in the TA).
__global__ __launch_bounds__(256) void qsum_kernel(
    const float* __restrict__ t0, const float* __restrict__ t1,
    const float* __restrict__ t2, const unsigned short* __restrict__ UwBF,
    float* __restrict__ Qsum)
{
    const int i2   = blockIdx.x;
    const int tid  = threadIdx.x;
    const int w    = tid >> 6;
    const int lane = tid & 63;
    const int l31  = lane & 31;
    const int half = lane >> 5;
    const int colq = w * 32 + l31;

    // [48 kg][32 b pad 33][8 j] bf16 = 50688 B
    __shared__ __align__(16) unsigned short Alds[48 * 33 * 8];

    #pragma unroll
    for (int mi = 0; mi < 3; ++mi) {
        const float* __restrict__ base = (mi == 0) ? t0 : (mi == 1) ? t1 : t2;
        #pragma unroll
        for (int i = 0; i < 4; ++i) {
            const int idx = i * 256 + tid;      // 0..1023 float4s
            const int b   = idx >> 5;
            const int q   = idx & 31;
            int row;
            if      (mi == 0) row = b;
            else if (mi == 1) row = b * 16 + (i2 >> 3);
            else              row = b * 128 + i2;
            const float4 v = *reinterpret_cast<const float4*>(
                base + (size_t)row * 128 + q * 4);
            ushort4 u;
            u.x = f2bf(v.x); u.y = f2bf(v.y); u.z = f2bf(v.z); u.w = f2bf(v.w);
            const int kg = mi * 16 + (q >> 1);
            *reinterpret_cast<ushort4*>(&Alds[(kg * 33 + b) * 8 + (q & 1) * 4]) = u;
        }
    }
    __syncthreads();

    floatx16 acc;
    #pragma unroll
    for (int r = 0; r < 16; ++r) acc[r] = 0.f;
    #pragma unroll
    for (int ks = 0; ks < 24; ++ks) {
        const int kg = 2 * ks + half;           // 0..47
        const short8 a = *reinterpret_cast<const short8*>(&Alds[(kg * 33 + l31) * 8]);
        const short8 bf = *reinterpret_cast<const short8*>(
            &UwBF[(((size_t)kg * 128) + colq) * 8]);
        acc = __builtin_amdgcn_mfma_f32_32x32x16_bf16(a, bf, acc, 0, 0, 0);
    }
    #pragma unroll
    for (int r = 0; r < 16; ++r) {
        const int brow = (r & 3) + 8 * (r >> 2) + 4 * half;   // batch
        Qsum[((size_t)i2 * 32 + brow) * 128 + colq] = acc[r];
    }
}

// ---------------- main: one block per node ---------------------------------
__global__ __launch_bounds__(256, 2) void tree_main(
    const float* __restrict__ t3,
    const float* __restrict__ Ub0, const float* __restrict__ Ub1,
    const float* __restrict__ Ub2, const float* __restrict__ Ub3,
    const float* __restrict__ Wup, const float* __restrict__ bbias,
    const unsigned short* __restrict__ FfusedBF,
    const unsigned short* __restrict__ UwBF,
    const float* __restrict__ Fbias, const float* __restrict__ Qsum,
    float* __restrict__ out)
{
    const int n    = blockIdx.x;
    const int tid  = threadIdx.x;
    const int w    = tid >> 6;
    const int lane = tid & 63;
    const int l31  = lane & 31;
    const int half = lane >> 5;
    const int colq = w * 32 + l31;

    // Union: T3lds [16 kg][33][8] u16 (8448B) / Ulds [16][65][8] u16 (16640B)
    __shared__ __align__(16) unsigned char smem_raw[16640];
    unsigned short* T3lds = (unsigned short*)smem_raw;
    unsigned short* Ulds  = (unsigned short*)smem_raw;

    // ---- stage t3 rows (32 b x 128 k) coalesced -> A-frag layout ---------
    #pragma unroll
    for (int i = 0; i < 4; ++i) {
        const int idx = i * 256 + tid;        // 0..1023 float4s
        const int b   = idx >> 5;
        const int q   = idx & 31;
        const float4 v = *reinterpret_cast<const float4*>(
            t3 + ((size_t)b * 1024 + n) * 128 + q * 4);
        ushort4 u;
        u.x = f2bf(v.x); u.y = f2bf(v.y); u.z = f2bf(v.z); u.w = f2bf(v.w);
        *reinterpret_cast<ushort4*>(&T3lds[((q >> 1) * 33 + b) * 8 + (q & 1) * 4]) = u;
    }
    __syncthreads();

    // ---- fused K-loop over t3's K=128 (8 steps of 16) --------------------
    // per ks: afk (1 ds_read_b128) feeds 3 MFMAs (qacc + 2 U^T tiles);
    // W-frags = 16 coalesced global dwords, prefetched depth-1.
    floatx16 qacc, accT0, accT1;
    #pragma unroll
    for (int r = 0; r < 16; ++r) { qacc[r] = 0.f; accT0[r] = 0.f; accT1[r] = 0.f; }

    const float* __restrict__ Wp0 = Wup + (size_t)n * 32768 + (half * 8) * 256 + w * 64 + l31;
    const float* __restrict__ Wp1 = Wp0 + 32;

    float p0[8], p1[8];
    #pragma unroll
    for (int jj = 0; jj < 8; ++jj) { p0[jj] = Wp0[jj * 256]; p1[jj] = Wp1[jj * 256]; }

    #pragma unroll
    for (int ks = 0; ks < 8; ++ks) {
        float n0[8], n1[8];
        if (ks < 7) {
            const int koff = (ks + 1) * 16 * 256;
            #pragma unroll
            for (int jj = 0; jj < 8; ++jj) {
                n0[jj] = Wp0[koff + jj * 256];
                n1[jj] = Wp1[koff + jj * 256];
            }
        }
        const short8 afk = *reinterpret_cast<const short8*>(
            &T3lds[((2 * ks + half) * 33 + l31) * 8]);
        const short8 bfu = *reinterpret_cast<const short8*>(
            &UwBF[(((size_t)(48 + 2 * ks + half) * 128) + colq) * 8]);
        short8 a0, a1;
        #pragma unroll
        for (int jj = 0; jj < 8; ++jj) {
            a0[jj] = (short)f2bf(p0[jj]);
            a1[jj] = (short)f2bf(p1[jj]);
        }
        qacc  = __builtin_amdgcn_mfma_f32_32x32x16_bf16(afk, bfu, qacc, 0, 0, 0);
        accT0 = __builtin_amdgcn_mfma_f32_32x32x16_bf16(a0, afk, accT0, 0, 0, 0);
        accT1 = __builtin_amdgcn_mfma_f32_32x32x16_bf16(a1, afk, accT1, 0, 0, 0);
        #pragma unroll
        for (int jj = 0; jj < 8; ++jj) { p0[jj] = n0[jj]; p1[jj] = n1[jj]; }
    }
    __syncthreads();     // all T3lds reads done before Ulds overlays

    // ---- U^T accs -> Ulds in GEMM3 A-frag layout (r2 = d*32 + batch) -----
    #pragma unroll
    for (int tt = 0; tt < 2; ++tt) {
        const floatx16 Av = tt ? accT1 : accT0;
        #pragma unroll
        for (int r = 0; r < 16; ++r) {
            const int cm = w * 64 + tt * 32 + ((r & 3) + 8 * (r >> 2) + 4 * half);
            const int d  = cm >> 7;
            const int cp = cm & 127;
            Ulds[(((cp >> 3) * 65) + d * 32 + l31) * 8 + (cp & 7)] = f2bf(Av[r]);
        }
    }
    __syncthreads();

    // ---- prefetch epilogue operands (hide under GEMM3's 16 MFMAs) --------
    const int i2 = n >> 3;
    float qs[16];
    #pragma unroll
    for (int r = 0; r < 16; ++r) {
        const int brow = (r & 3) + 8 * (r >> 2) + 4 * half;
        qs[r] = Qsum[((size_t)i2 * 32 + brow) * 128 + colq];
    }
    const float ubsum = Ub0[colq] + Ub1[colq] + Ub2[colq] + Ub3[colq] + Fbias[colq];
    const float bb0 = bbias[(size_t)(2 * n + 0) * 128 + colq];
    const float bb1 = bbias[(size_t)(2 * n + 1) * 128 + colq];

    // ---- GEMM 3: out = U2 @ Ffused  (M64 N128 K128) ----------------------
    floatx16 o0, o1;
    #pragma unroll
    for (int r = 0; r < 16; ++r) { o0[r] = 0.f; o1[r] = 0.f; }
    #pragma unroll
    for (int ks = 0; ks < 8; ++ks) {
        const int kg2 = 2 * ks + half;
        const short8 a0 = *reinterpret_cast<const short8*>(&Ulds[(kg2 * 65 + l31) * 8]);
        const short8 a1 = *reinterpret_cast<const short8*>(&Ulds[(kg2 * 65 + 32 + l31) * 8]);
        const short8 bf = *reinterpret_cast<const short8*>(
            &FfusedBF[(((size_t)kg2 * 128) + colq) * 8]);
        o0 = __builtin_amdgcn_mfma_f32_32x32x16_bf16(a0, bf, o0, 0, 0, 0);
        o1 = __builtin_amdgcn_mfma_f32_32x32x16_bf16(a1, bf, o1, 0, 0, 0);
    }

    // ---- epilogue: + qacc + Qsum + biases, LeakyReLU(0.2), store ---------
    #pragma unroll
    for (int r = 0; r < 16; ++r) {
        const int brow = (r & 3) + 8 * (r >> 2) + 4 * half;
        const float addc = qacc[r] + ubsum + qs[r];
        float v0 = o0[r] + addc + bb0;
        float v1 = o1[r] + addc + bb1;
        v0 = (v0 >= 0.f) ? v0 : 0.2f * v0;
        v1 = (v1 >= 0.f) ? v1 : 0.2f * v1;
        const size_t idx0 = ((size_t)brow * 2048 + 2 * n) * 128 + colq;
        out[idx0]       = v0;
        out[idx0 + 128] = v1;
    }
}

extern "C" void kernel_launch(void* const* d_in, const int* in_sizes, int n_in,
                              void* d_out, int out_size, void* d_ws, size_t ws_size,
                              hipStream_t stream) {
    const float* t0  = (const float*)d_in[0];
    const float* t1  = (const float*)d_in[1];
    const float* t2  = (const float*)d_in[2];
    const float* t3  = (const float*)d_in[3];
    const float* Uw0 = (const float*)d_in[4];
    const float* Ub0 = (const float*)d_in[5];
    const float* Uw1 = (const float*)d_in[6];
    const float* Ub1 = (const float*)d_in[7];
    const float* Uw2 = (const float*)d_in[8];
    const float* Ub2 = (const float*)d_in[9];
    const float* Uw3 = (const float*)d_in[10];
    const float* Ub3 = (const float*)d_in[11];
    const float* Wup = (const float*)d_in[12];
    const float* Fw0 = (const float*)d_in[13];
    const float* Fb0 = (const float*)d_in[14];
    const float* Fw1 = (const float*)d_in[15];
    const float* Fb1 = (const float*)d_in[16];
    const float* bb  = (const float*)d_in[17];

    float* ws = (float*)d_ws;
    float* Qsum           = ws + QS_OFF;     // overlays P (dead after p2)
    float* Fbias          = ws + FB_OFF;
    unsigned short* FfBF  = (unsigned short*)(ws + FF_OFF);
    unsigned short* UwBF  = (unsigned short*)(ws + UW_OFF);

    ffused_p1<<<dim3(8, 129), 256, 0, stream>>>(Fw0, Fb0, Fw1, Qsum);
    ffused_p2<<<65, 256, 0, stream>>>(Qsum, Fb1, FfBF, Fbias);
    uwbf_kernel<<<64, 256, 0, stream>>>(Uw0, Uw1, Uw2, Uw3, UwBF);
    qsum_kernel<<<128, 256, 0, stream>>>(t0, t1, t2, UwBF, Qsum);
    tree_main<<<1024, 256, 0, stream>>>(t3,
                                        Ub0, Ub1, Ub2, Ub3,
                                        Wup, bb, FfBF, UwBF, Fbias, Qsum,
                                        (float*)d_out);
}